// Round 6
// baseline (322.104 us; speedup 1.0000x reference)
//
#include <hip/hip_runtime.h>
#include <math.h>
#include <stdint.h>

// Octonion product via Cayley-Dickson over quaternions (matches reference's
// _oct_structure exactly).
__device__ __forceinline__ void qmul(float w1, float x1, float y1, float z1,
                                     float w2, float x2, float y2, float z2,
                                     float& w, float& x, float& y, float& z) {
    w = w1 * w2 - x1 * x2 - y1 * y2 - z1 * z2;
    x = w1 * x2 + x1 * w2 + y1 * z2 - z1 * y2;
    y = w1 * y2 - x1 * z2 + y1 * w2 + z1 * x2;
    z = w1 * z2 + x1 * y2 - y1 * x2 + z1 * w2;
}

typedef __attribute__((address_space(3))) uint32_t lds_u32;
typedef const __attribute__((address_space(1))) uint32_t glb_u32;

#define PAGE 65               // granules (float4) per DMA page: 64 data + 1 pad
#define BUFG (14 * PAGE)      // 910 granules = 14560 B per tile buffer

// Persistent 1-wave blocks, LDS DOUBLE-BUFFER software pipeline:
//   per tile: issue tile k+1's 14 global_load_lds (HBM->LDS DMA, zero VGPRs)
//   into buf B, then s_waitcnt vmcnt(14) -- drains ONLY tile k's loads (oldest
//   first, m135), leaving the new 14 in flight across the whole compute phase.
// This removes the load-burst/drain/compute serialization that pinned rounds
// 1/2/3/5 at ~92us (2.5x the 36us HBM floor).
// Page pad (65 granules): readback granule = g + g/64 rotates the 16B bank
// group by page -> ~uniform over 8 groups (the linear layout had 16 lanes on
// 4 of 8 groups).
__global__ __launch_bounds__(64) void oct_fano_kernel(
    const float* __restrict__ in,    // (B, 7, 8) fp32
    const float* __restrict__ logs,  // scalar log_sensitivity
    float* __restrict__ out,         // (B,) fp32
    int B, int ntiles) {
    __shared__ __align__(16) float4 lds4[2 * BUFG];  // 29120 B -> 5 blocks/CU

    const int t = threadIdx.x;               // lane
    const int G = gridDim.x;                 // persistent stride (tiles)
    const float4* gp = (const float4*)in;
    const long gmax = (long)B * 14 - 1;
    const float sens = __expf(logs[0]);

    int tile = blockIdx.x;
    int p = 0;

    // ---- prologue: DMA tile 0 of this wave into buffer 0 ----
    if (tile < ntiles) {
        const long gbase = (long)tile * 896;
#pragma unroll
        for (int c = 0; c < 14; c++) {
            long idx = gbase + c * 64 + t;
            if (idx > gmax) idx = gmax;      // tail clamp (dup load, harmless)
            __builtin_amdgcn_global_load_lds((glb_u32*)(gp + idx),
                                             (lds_u32*)&lds4[c * PAGE], 16, 0, 0);
        }
    }

    while (tile < ntiles) {
        const int next = tile + G;
        const float4* __restrict__ cur = &lds4[p * BUFG];

        // ---- issue NEXT tile's DMA into the other buffer, then wait only
        //      for the CURRENT tile's 14 loads (vmcnt(14)) ----
        if (next < ntiles) {
            float4* nxt = &lds4[(p ^ 1) * BUFG];
            const long gbase = (long)next * 896;
#pragma unroll
            for (int c = 0; c < 14; c++) {
                long idx = gbase + c * 64 + t;
                if (idx > gmax) idx = gmax;
                __builtin_amdgcn_global_load_lds((glb_u32*)(gp + idx),
                                                 (lds_u32*)&nxt[c * PAGE], 16, 0, 0);
            }
            // vmcnt(14): 14 newest stay in flight; older (cur tile + prev
            // store) drain. lgkmcnt=15, expcnt=7 = no-wait.
            __builtin_amdgcn_s_waitcnt(0x0F7E);
        } else {
            __builtin_amdgcn_s_waitcnt(0x0F70);  // last tile: vmcnt(0)
        }
        __builtin_amdgcn_sched_barrier(0);       // pin ds_reads after the wait

        const int nb = min(64, B - (tile << 6));
        if (t < nb) {
            // ---- readback batch t: granule g=t*14+k lives at g + g/64 ----
            float x[7][8];
#pragma unroll
            for (int k = 0; k < 14; k++) {
                int g = t * 14 + k;
                float4 q = cur[g + (g >> 6)];
                int r = k >> 1;
                int c = (k & 1) * 4;
                x[r][c + 0] = q.x;
                x[r][c + 1] = q.y;
                x[r][c + 2] = q.z;
                x[r][c + 3] = q.w;
            }

            // normalize rows (rsqrt: rel err ~1e-6 << 1.7e-2 threshold)
#pragma unroll
            for (int r = 0; r < 7; r++) {
                float s = 0.f;
#pragma unroll
                for (int c = 0; c < 8; c++) s += x[r][c] * x[r][c];
                float inv = rsqrtf(fmaxf(s, 1e-24f));
#pragma unroll
                for (int c = 0; c < 8; c++) x[r][c] *= inv;
            }

            // 7 Fano lines: (i, j, k) = (l, (l+1)%7, (l+3)%7)
            float total = 0.f;
#pragma unroll
            for (int l = 0; l < 7; l++) {
                const float* a = x[l];
                const float* bb = x[(l + 1) % 7];
                const float* ck = x[(l + 3) % 7];

                float p0, p1, p2, p3, p4, p5, p6, p7;
                float t0, t1, t2, t3;
                // c1 = qmul(a1, b1) - qmul(conj(b2), a2)
                qmul(a[0], a[1], a[2], a[3], bb[0], bb[1], bb[2], bb[3], p0, p1, p2, p3);
                qmul(bb[4], -bb[5], -bb[6], -bb[7], a[4], a[5], a[6], a[7], t0, t1, t2, t3);
                p0 -= t0; p1 -= t1; p2 -= t2; p3 -= t3;
                // c2 = qmul(b2, a1) + qmul(a2, conj(b1))
                qmul(bb[4], bb[5], bb[6], bb[7], a[0], a[1], a[2], a[3], p4, p5, p6, p7);
                qmul(a[4], a[5], a[6], a[7], bb[0], -bb[1], -bb[2], -bb[3], t0, t1, t2, t3);
                p4 += t0; p5 += t1; p6 += t2; p7 += t3;

                float d0 = p0 - ck[0], d1 = p1 - ck[1], d2 = p2 - ck[2], d3 = p3 - ck[3];
                float d4 = p4 - ck[4], d5 = p5 - ck[5], d6 = p6 - ck[6], d7 = p7 - ck[7];
                total += d0 * d0 + d1 * d1 + d2 * d2 + d3 * d3 +
                         d4 * d4 + d5 * d5 + d6 * d6 + d7 * d7;
            }

            float avg = total * (1.0f / 7.0f);
            float phi = -__logf(avg + 1e-8f) * sens;
            phi = fminf(fmaxf(phi, 0.0f), 10.0f);
            out[(tile << 6) + t] = phi;
        }

        p ^= 1;
        tile = next;
    }
}

extern "C" void kernel_launch(void* const* d_in, const int* in_sizes, int n_in,
                              void* d_out, int out_size, void* d_ws, size_t ws_size,
                              hipStream_t stream) {
    const float* states = (const float*)d_in[0];
    const float* logs = (const float*)d_in[1];
    float* out = (float*)d_out;
    int B = in_sizes[0] / 56;                // 7*8 floats per batch
    int ntiles = (B + 63) / 64;              // 64-batch tiles, 1 wave each
    int nblocks = 256 * 5;                   // 5 single-wave blocks/CU (LDS cap)
    if (nblocks > ntiles) nblocks = ntiles;
    oct_fano_kernel<<<nblocks, 64, 0, stream>>>(states, logs, out, B, ntiles);
}